// Round 6
// baseline (276.426 us; speedup 1.0000x reference)
//
#include <hip/hip_runtime.h>
#include <math.h>

#define N_QUBITS 24
#define N_BLOCKS 4
#define NSTATE (1 << N_QUBITS)

// Qubit q <-> flat-index bit (23 - q)  (row-major reshape of (2,)*24).
// Per block, gates reordered (valid by commutation) into the staircase:
//   RY(0); for q=1..23: RY(q); CNOT(q-1, q)
// Ping-pong buffers, alternating layouts (race-free: src != dst).
//   standard layout: addr = e23..e0
//   pi layout:       addr = e[6..14]<<15 | H<<6 | e[0..5],  H bit k = e(15+k)
//   P1  (qubits 0..8):  d_out std (scattered 256B reads) -> d_ws pi (CONTIGUOUS)
//   P23 (qubits 9..23): d_ws pi (scattered 256B reads) -> d_out std (CONTIGUOUS)
// P23/init use 1024-thread wgs (16 waves/CU at 128 KiB LDS) with 32 regs/thread;
// qubit 14's gate is a lane-shuffle gate after T1 (e9,e10 = lane bits 0,1 there).
// Block 0 replaced by pass23_init (in-LDS 9-qubit sim + tail) -> d_out.

// LDS swizzle; for every transpose pattern below the bank projection onto the
// wave's lane bits has rank >= 5 -> <=2-way access (free).
#define SWZ(e) ((e) ^ (((e) >> 6) & 31) ^ (((e) >> 11) & 31))

// ---- 64-reg helpers (pass1) ----
template <int B>
__device__ __forceinline__ void pair_bit(float (&a)[64], float s, float c, int swap) {
#pragma unroll
    for (int g = 0; g < 32; ++g) {
        int r0 = ((g >> B) << (B + 1)) | (g & ((1 << B) - 1));
        int r1 = r0 | (1 << B);
        float v0 = a[r0], v1 = a[r1];
        float o0 = c * v0 - s * v1;
        float o1 = s * v0 + c * v1;
        a[r0] = swap ? o1 : o0;
        a[r1] = swap ? o0 : o1;
    }
}
__device__ __forceinline__ void pair_top(float (&a)[64], float s, float c, int swap) {
    pair_bit<5>(a, s, c, swap);
}
template <int BT>
__device__ __forceinline__ void quad_gate(float (&a)[64], float s, float c) {
#pragma unroll
    for (int g = 0; g < 16; ++g) {
        int lo  = g & ((1 << BT) - 1);
        int r00 = ((g >> BT) << (BT + 2)) | lo;
        int r01 = r00 | (1 << BT);
        int r10 = r00 | (2 << BT);
        int r11 = r00 | (3 << BT);
        float v00 = a[r00], v01 = a[r01], v10 = a[r10], v11 = a[r11];
        a[r00] = c * v00 - s * v01;
        a[r01] = s * v00 + c * v01;
        a[r10] = s * v10 + c * v11;   // ctrl=1 half: RY then swap (CNOT)
        a[r11] = c * v10 - s * v11;
    }
}

// ---- 32-reg helpers (pass23 tail, 1024 threads) ----
template <int B>
__device__ __forceinline__ void pair_bit32(float (&a)[32], float s, float c, int swap) {
#pragma unroll
    for (int g = 0; g < 16; ++g) {
        int r0 = ((g >> B) << (B + 1)) | (g & ((1 << B) - 1));
        int r1 = r0 | (1 << B);
        float v0 = a[r0], v1 = a[r1];
        float o0 = c * v0 - s * v1;
        float o1 = s * v0 + c * v1;
        a[r0] = swap ? o1 : o0;
        a[r1] = swap ? o0 : o1;
    }
}
template <int BT>
__device__ __forceinline__ void quad_gate32(float (&a)[32], float s, float c) {
#pragma unroll
    for (int g = 0; g < 8; ++g) {
        int lo  = g & ((1 << BT) - 1);
        int r00 = ((g >> BT) << (BT + 2)) | lo;
        int r01 = r00 | (1 << BT);
        int r10 = r00 | (2 << BT);
        int r11 = r00 | (3 << BT);
        float v00 = a[r00], v01 = a[r01], v10 = a[r10], v11 = a[r11];
        a[r00] = c * v00 - s * v01;
        a[r01] = s * v00 + c * v01;
        a[r10] = s * v10 + c * v11;
        a[r11] = c * v10 - s * v11;
    }
}

// ---------------- Pass 1 (std -> pi): qubits 0..8 (bits 15..23) ----------------
// 512 threads x 64 regs; blk = e6..14. Phase A: regs = e18..23, w = e15..17,
// lane = e0..5. Phase B: regs r' = (e23,e17,e16,e15,e22,e21), w = e18..20.
// T1 chunked by e23: 2 rounds x 16K floats = 64 KiB LDS -> 2 wg/CU.
__global__ __launch_bounds__(512)
void pass1_pi_kernel(const float* __restrict__ src, float* __restrict__ dst,
                     const float* __restrict__ angles, int blk_b) {
    __shared__ float lds[16384];
    const int tid  = threadIdx.x;
    const int lane = tid & 63;
    const int w    = tid >> 6;
    const int blk  = blockIdx.x;                 // e6..14
    const float* ang = angles + blk_b * N_QUBITS;
    const size_t lowbase = ((size_t)blk << 6) | (size_t)lane;

    float a[64];
#pragma unroll
    for (int r = 0; r < 64; ++r)
        a[r] = src[((size_t)((r << 3) | w) << 15) | lowbase];

    float s, c;
    sincosf(0.5f * ang[0], &s, &c); pair_top(a, s, c, 0);
    sincosf(0.5f * ang[1], &s, &c); quad_gate<4>(a, s, c);
    sincosf(0.5f * ang[2], &s, &c); quad_gate<3>(a, s, c);
    sincosf(0.5f * ang[3], &s, &c); quad_gate<2>(a, s, c);
    sincosf(0.5f * ang[4], &s, &c); quad_gate<1>(a, s, c);
    sincosf(0.5f * ang[5], &s, &c); quad_gate<0>(a, s, c);

#pragma unroll
    for (int cb = 0; cb < 2; ++cb) {
        if (cb) __syncthreads();
#pragma unroll
        for (int rr = 0; rr < 32; ++rr)
            lds[(rr << 9) | (w << 6) | lane] = a[(cb << 5) | rr];
        __syncthreads();
#pragma unroll
        for (int q = 0; q < 32; ++q) {
            int h = (((q >> 1) & 1) << 13) | ((q & 1) << 12) | (w << 9)
                  | (((q >> 4) & 1) << 8) | (((q >> 3) & 1) << 7) | (((q >> 2) & 1) << 6)
                  | lane;
            a[(cb << 5) | q] = lds[h];
        }
    }

    sincosf(0.5f * ang[6], &s, &c); pair_bit<4>(a, s, c, w & 1);
    sincosf(0.5f * ang[7], &s, &c); quad_gate<3>(a, s, c);
    sincosf(0.5f * ang[8], &s, &c); quad_gate<2>(a, s, c);

#pragma unroll
    for (int r = 0; r < 64; ++r) {
        int H = (((r >> 5) & 1) << 8) | (((r >> 1) & 1) << 7) | ((r & 1) << 6) | (w << 3)
              | (((r >> 4) & 1) << 2) | (((r >> 3) & 1) << 1) | ((r >> 2) & 1);
        dst[((size_t)blk << 15) | (H << 6) | lane] = a[r];
    }
}

// ---------------- Pass 2+3 tail (1024 threads): qubits 9..23 -------------------
// Local h (15 bits), thread = (w=tid>>6 in 0..15, lane=tid&63), 32 regs.
// L0 (entry): regs = e10..14, w = e6..9, lane = e0..5.
// T1 -> L1:   regs = e4..8,  lane = e9..14, w = e0..3.
//   (then qubit 14 as lane-shuffle gate: tgt e9 = lane0, ctrl e10 = lane1)
// T2 -> L2:   regs = e0..4,  lane = e5..10, w = e11..14.
// T3 -> L3:   regs = e6..10, lane = e0..5,  w = e11..14  (contiguous store).
template <bool SQUARE>
__device__ __forceinline__ void p23_tail(float (&a)[32], float* __restrict__ lds,
                                         float* __restrict__ base, const float* ang,
                                         int lane, int w, int c15) {
    float s, c;
    // phase 1: qubits 9..13 on regs (e10..14)
    sincosf(0.5f * ang[9], &s, &c);  pair_bit32<4>(a, s, c, c15);   // RY(9)+CNOT(8,9)
    sincosf(0.5f * ang[10], &s, &c); quad_gate32<3>(a, s, c);
    sincosf(0.5f * ang[11], &s, &c); quad_gate32<2>(a, s, c);
    sincosf(0.5f * ang[12], &s, &c); quad_gate32<1>(a, s, c);
    sincosf(0.5f * ang[13], &s, &c); quad_gate32<0>(a, s, c);

    // T1: L0 h=(r<<10)|(w<<6)|lane -> L1 h=(lane<<9)|(q<<4)|w
#pragma unroll
    for (int r = 0; r < 32; ++r) {
        int h = (r << 10) | (w << 6) | lane;
        lds[SWZ(h)] = a[r];
    }
    __syncthreads();
#pragma unroll
    for (int q = 0; q < 32; ++q) {
        int h = (lane << 9) | (q << 4) | w;
        a[q] = lds[SWZ(h)];
    }

    // qubit 14: RY tgt e9 = lane0, then CNOT(13,14) ctrl e10 = lane1
    sincosf(0.5f * ang[14], &s, &c);
    {
        const int b   = lane & 1;
        const int sel = b ^ ((lane >> 1) & 1);
#pragma unroll
        for (int r = 0; r < 32; ++r) {
            float v = a[r], p = __shfl_xor(v, 1);
            float v0 = b ? p : v, v1 = b ? v : p;
            float o0 = c * v0 - s * v1;
            float o1 = s * v0 + c * v1;
            a[r] = sel ? o1 : o0;
        }
    }

    // phase 2: qubits 15..19 on regs (e4..8)
    sincosf(0.5f * ang[15], &s, &c); pair_bit32<4>(a, s, c, lane & 1);  // ctrl e9
    sincosf(0.5f * ang[16], &s, &c); quad_gate32<3>(a, s, c);
    sincosf(0.5f * ang[17], &s, &c); quad_gate32<2>(a, s, c);
    sincosf(0.5f * ang[18], &s, &c); quad_gate32<1>(a, s, c);
    sincosf(0.5f * ang[19], &s, &c); quad_gate32<0>(a, s, c);

    // T2: L1 h=(lane<<9)|(q<<4)|w -> L2 h=(w<<11)|(lane<<5)|p
    __syncthreads();
#pragma unroll
    for (int q = 0; q < 32; ++q) {
        int h = (lane << 9) | (q << 4) | w;
        lds[SWZ(h)] = a[q];
    }
    __syncthreads();
#pragma unroll
    for (int p = 0; p < 32; ++p) {
        int h = (w << 11) | (lane << 5) | p;
        a[p] = lds[SWZ(h)];
    }

    // phase 3: qubits 20..23 on regs (e0..4)
    sincosf(0.5f * ang[20], &s, &c); quad_gate32<3>(a, s, c);   // ctrl e4, tgt e3
    sincosf(0.5f * ang[21], &s, &c); quad_gate32<2>(a, s, c);
    sincosf(0.5f * ang[22], &s, &c); quad_gate32<1>(a, s, c);
    sincosf(0.5f * ang[23], &s, &c); quad_gate32<0>(a, s, c);

    if (SQUARE) {
#pragma unroll
        for (int p = 0; p < 32; ++p) a[p] *= a[p];
    }

    // T3: L2 h=(w<<11)|(lane<<5)|p -> L3 h=(w<<11)|(q<<6)|lane
    __syncthreads();
#pragma unroll
    for (int p = 0; p < 32; ++p) {
        int h = (w << 11) | (lane << 5) | p;
        lds[SWZ(h)] = a[p];
    }
    __syncthreads();
#pragma unroll
    for (int q = 0; q < 32; ++q) {
        int h = (w << 11) | (q << 6) | lane;
        a[q] = lds[SWZ(h)];
    }

    // store STANDARD: contiguous 128-KiB workgroup footprint
#pragma unroll
    for (int q = 0; q < 32; ++q)
        base[(w << 11) | (q << 6) | lane] = a[q];
}

// P23: read pi from src, write standard to dst. 1024 threads.
template <bool SQUARE>
__global__ __launch_bounds__(1024)
void pass23_pi_kernel(const float* __restrict__ src, float* __restrict__ dst,
                      const float* __restrict__ angles, int blk_b) {
    __shared__ float lds[32768];
    const int tid  = threadIdx.x;
    const int lane = tid & 63;
    const int w    = tid >> 6;                   // 0..15
    const int chunk = blockIdx.x;                // = H = e15..23
    float* __restrict__ base = dst + ((size_t)chunk << 15);
    const int c15 = chunk & 1;                   // e15
    const float* ang = angles + blk_b * N_QUBITS;

    float a[32];
    // read pi: addr = (B = e6..14 = r<<4|w)<<15 | chunk<<6 | lane
#pragma unroll
    for (int r = 0; r < 32; ++r)
        a[r] = src[((size_t)((r << 4) | w) << 15) | ((size_t)chunk << 6) | (size_t)lane];

    p23_tail<SQUARE>(a, lds, base, ang, lane, w, c15);
}

// Block 0 fused: after qubits 0..8 from |0..0>, state = f9[e15..23] * delta(e0..14).
__global__ __launch_bounds__(1024)
void pass23_init_kernel(float* __restrict__ dst, const float* __restrict__ angles) {
    __shared__ float lds[32768];
    const int tid  = threadIdx.x;
    const int lane = tid & 63;
    const int w    = tid >> 6;
    const int chunk = blockIdx.x;
    float* __restrict__ base = dst + ((size_t)chunk << 15);
    const float* ang = angles;                   // block 0
    float s, c;

    float* f = lds;
    if (tid < 512) f[tid] = 0.0f;
    __syncthreads();
    if (tid == 0) f[0] = 1.0f;
    __syncthreads();
    sincosf(0.5f * ang[0], &s, &c);
    if (tid < 256) {
        float v0 = f[tid], v1 = f[tid | 256];
        f[tid]       = c * v0 - s * v1;
        f[tid | 256] = s * v0 + c * v1;
    }
    __syncthreads();
    for (int q = 1; q <= 8; ++q) {
        sincosf(0.5f * ang[q], &s, &c);
        int bt = 8 - q;
        if (tid < 128) {
            int lo  = tid & ((1 << bt) - 1);
            int r00 = ((tid >> bt) << (bt + 2)) | lo;
            int r01 = r00 | (1 << bt);
            int r10 = r00 | (2 << bt);
            int r11 = r00 | (3 << bt);
            float v00 = f[r00], v01 = f[r01], v10 = f[r10], v11 = f[r11];
            f[r00] = c * v00 - s * v01;
            f[r01] = s * v00 + c * v01;
            f[r10] = s * v10 + c * v11;
            f[r11] = c * v10 - s * v11;
        }
        __syncthreads();
    }
    const float amp = f[chunk];
    __syncthreads();                             // lds reused by the tail

    float a[32];
#pragma unroll
    for (int r = 0; r < 32; ++r) a[r] = 0.0f;
    if (tid == 0) a[0] = amp;                    // h = 0 -> r = 0, w = 0, lane = 0

    p23_tail<false>(a, lds, base, ang, lane, w, chunk & 1);
}

extern "C" void kernel_launch(void* const* d_in, const int* in_sizes, int n_in,
                              void* d_out, int out_size, void* d_ws, size_t ws_size,
                              hipStream_t stream) {
    const float* angles = (const float*)d_in[0];
    float* out = (float*)d_out;
    float* ws  = (float*)d_ws;

    pass23_init_kernel<<<NSTATE >> 15, 1024, 0, stream>>>(out, angles);

    for (int b = 1; b < N_BLOCKS; ++b) {
        const bool last = (b == N_BLOCKS - 1);
        pass1_pi_kernel<<<NSTATE >> 15, 512, 0, stream>>>(out, ws, angles, b);
        if (last)
            pass23_pi_kernel<true><<<NSTATE >> 15, 1024, 0, stream>>>(ws, out, angles, b);
        else
            pass23_pi_kernel<false><<<NSTATE >> 15, 1024, 0, stream>>>(ws, out, angles, b);
    }
}